// Round 1
// baseline (1772.739 us; speedup 1.0000x reference)
//
#include <hip/hip_runtime.h>

namespace {
constexpr int N_NODES = 100000;
constexpr int N_EDGES = 640000;
}

// ---------------- degree / norm ----------------

__global__ void k_init_deg(float* __restrict__ deg) {
  int i = blockIdx.x * 256 + threadIdx.x;
  if (i < N_NODES) deg[i] = 1.0f;  // self-loop
}

__global__ void k_count_deg(const int* __restrict__ col, float* __restrict__ deg) {
  int i = blockIdx.x * 256 + threadIdx.x;
  if (i < N_EDGES) atomicAdd(&deg[col[i]], 1.0f);
}

__global__ void k_dinv(float* __restrict__ deg) {
  int i = blockIdx.x * 256 + threadIdx.x;
  if (i < N_NODES) deg[i] = rsqrtf(deg[i]);  // deg >= 1 always
}

// ---------------- GEMM: Y[n x kout] = X[n x 128] @ W[128 x kout] ----------------
// 64-col tile per blockIdx.y, 32-row chunk, thread = 2 rows x 4 cols.

template <bool RELU_IN>
__global__ __launch_bounds__(256) void k_gemm(const float* __restrict__ X,
                                              const float* __restrict__ W,
                                              float* __restrict__ Y,
                                              int n_rows, int kout) {
  constexpr int K = 128;
  constexpr int CT = 64;    // col tile
  constexpr int ROWS = 32;  // row chunk
  constexpr int XS = K + 4; // padded stride (132 floats, 16B-aligned rows, conflict-free)
  __shared__ float Wl[K][CT];      // 32 KB
  __shared__ float Xl[ROWS][XS];   // 16.5 KB

  const int tid = threadIdx.x;
  const int col0 = blockIdx.y * CT;

  // Load W tile (128 x 64)
  for (int i = tid; i < K * CT / 4; i += 256) {
    int k = i >> 4, q = i & 15;
    *(float4*)&Wl[k][q * 4] = *(const float4*)&W[k * kout + col0 + q * 4];
  }

  const int colq = tid & 15;  // 16 col quads
  const int rs = tid >> 4;    // 16 row pairs
  const int r0 = rs * 2, r1 = rs * 2 + 1;
  const int nchunks = (n_rows + ROWS - 1) / ROWS;

  for (int chunk = blockIdx.x; chunk < nchunks; chunk += gridDim.x) {
    const int base = chunk * ROWS;
    const int nr = min(ROWS, n_rows - base);
    __syncthreads();  // protects Xl reuse; first pass also orders after W load-start
    for (int i = tid; i < ROWS * K / 4; i += 256) {
      int r = i >> 5, q = i & 31;
      if (r < nr) {
        float4 v = *(const float4*)&X[(long long)(base + r) * K + q * 4];
        if (RELU_IN) {
          v.x = fmaxf(v.x, 0.f); v.y = fmaxf(v.y, 0.f);
          v.z = fmaxf(v.z, 0.f); v.w = fmaxf(v.w, 0.f);
        }
        *(float4*)&Xl[r][q * 4] = v;
      }
    }
    __syncthreads();

    float4 a0 = {0, 0, 0, 0}, a1 = {0, 0, 0, 0};
#pragma unroll 8
    for (int k = 0; k < K; ++k) {
      float4 w = *(float4*)&Wl[k][colq * 4];
      float x0 = Xl[r0][k], x1 = Xl[r1][k];
      a0.x += x0 * w.x; a0.y += x0 * w.y; a0.z += x0 * w.z; a0.w += x0 * w.w;
      a1.x += x1 * w.x; a1.y += x1 * w.y; a1.z += x1 * w.z; a1.w += x1 * w.w;
    }
    if (r0 < nr) *(float4*)&Y[(long long)(base + r0) * kout + col0 + colq * 4] = a0;
    if (r1 < nr) *(float4*)&Y[(long long)(base + r1) * kout + col0 + colq * 4] = a1;
  }
}

// ---------------- out[i] = bias + dinv[i]^2 * h[i]  (self-loop + bias, full overwrite) ---------

template <int C>
__global__ void k_self_bias(const float* __restrict__ h, const float* __restrict__ bias,
                            const float* __restrict__ dinv, float* __restrict__ out) {
  constexpr int Q = C / 4;
  int idx = blockIdx.x * 256 + threadIdx.x;
  if (idx >= N_NODES * Q) return;
  int node = idx / Q;
  int q = idx % Q;
  float d = dinv[node];
  float w = d * d;
  float4 hv = *(const float4*)&h[(long long)node * C + q * 4];
  float4 bv = *(const float4*)&bias[q * 4];
  float4 o = {bv.x + w * hv.x, bv.y + w * hv.y, bv.z + w * hv.z, bv.w + w * hv.w};
  *(float4*)&out[(long long)node * C + q * 4] = o;
}

// ---------------- edge scatter: out[col] += dinv[row]*dinv[col]*h[row] ----------------

template <int C>
__global__ void k_scatter(const int* __restrict__ rows, const int* __restrict__ cols,
                          const float* __restrict__ dinv, const float* __restrict__ h,
                          float* __restrict__ out) {
  constexpr int Q = C / 4;
  long long idx = blockIdx.x * 256LL + threadIdx.x;
  if (idx >= (long long)N_EDGES * Q) return;
  int e = (int)(idx / Q);
  int q = (int)(idx % Q);
  int r = rows[e], c = cols[e];
  float nm = dinv[r] * dinv[c];
  float4 hv = *(const float4*)&h[(long long)r * C + q * 4];
  float* dst = &out[(long long)c * C + q * 4];
  atomicAdd(dst + 0, nm * hv.x);
  atomicAdd(dst + 1, nm * hv.y);
  atomicAdd(dst + 2, nm * hv.z);
  atomicAdd(dst + 3, nm * hv.w);
}

// ---------------- launch ----------------

extern "C" void kernel_launch(void* const* d_in, const int* in_sizes, int n_in,
                              void* d_out, int out_size, void* d_ws, size_t ws_size,
                              hipStream_t stream) {
  const float* x = (const float*)d_in[0];
  const int* ei = (const int*)d_in[1];
  const int* erow = ei;              // sources
  const int* ecol = ei + N_EDGES;    // targets
  const float* W1 = (const float*)d_in[2];
  const float* b1 = (const float*)d_in[3];
  const float* W2 = (const float*)d_in[4];
  const float* b2 = (const float*)d_in[5];
  float* out = (float*)d_out;

  char* ws = (char*)d_ws;
  float* dinv = (float*)ws;                                  // N floats (used as deg first)
  float* h1 = (float*)(ws + 400000);                         // N*128
  float* agg1 = (float*)(ws + 400000 + 51200000LL);          // N*128
  float* h2 = (float*)(ws + 400000 + 2 * 51200000LL);        // N*64

  // norm
  k_init_deg<<<(N_NODES + 255) / 256, 256, 0, stream>>>(dinv);
  k_count_deg<<<(N_EDGES + 255) / 256, 256, 0, stream>>>(ecol, dinv);
  k_dinv<<<(N_NODES + 255) / 256, 256, 0, stream>>>(dinv);

  // layer 1
  dim3 g1((N_NODES + 31) / 32, 2);
  k_gemm<false><<<g1, 256, 0, stream>>>(x, W1, h1, N_NODES, 128);
  k_self_bias<128><<<(N_NODES * 32 + 255) / 256, 256, 0, stream>>>(h1, b1, dinv, agg1);
  k_scatter<128><<<(int)(((long long)N_EDGES * 32 + 255) / 256), 256, 0, stream>>>(
      erow, ecol, dinv, h1, agg1);

  // layer 2 (ReLU fused into GEMM input load)
  dim3 g2((N_NODES + 31) / 32, 1);
  k_gemm<true><<<g2, 256, 0, stream>>>(agg1, W2, h2, N_NODES, 64);
  k_self_bias<64><<<(N_NODES * 16 + 255) / 256, 256, 0, stream>>>(h2, b2, dinv, out);
  k_scatter<64><<<(int)(((long long)N_EDGES * 16 + 255) / 256), 256, 0, stream>>>(
      erow, ecol, dinv, h2, out);
}

// Round 2
// 265.236 us; speedup vs baseline: 6.6836x; 6.6836x over previous
//
#include <hip/hip_runtime.h>

namespace {
constexpr int N_NODES = 100000;
constexpr int N_EDGES = 640000;
constexpr int SCAN_B = 1024;
constexpr int NSCANB = (N_NODES + SCAN_B - 1) / SCAN_B;  // 98
}

// ---------------- CSR build (int atomics only, ~5 MB traffic) ----------------

__global__ void k_zero_i32(int* __restrict__ p, int n) {
  int i = blockIdx.x * 256 + threadIdx.x;
  if (i < n) p[i] = 0;
}

__global__ void k_hist(const int* __restrict__ col, int* __restrict__ deg) {
  int i = blockIdx.x * 256 + threadIdx.x;
  if (i < N_EDGES) atomicAdd(&deg[col[i]], 1);
}

// block scans 1024 elems: per-thread serial 4 + Hillis-Steele over 256 thread sums
__global__ __launch_bounds__(256) void k_scan1(const int* __restrict__ deg,
                                               int* __restrict__ excl,
                                               int* __restrict__ bsum) {
  __shared__ int tmp[256];
  int t = threadIdx.x;
  int base = blockIdx.x * SCAN_B + t * 4;
  int v[4];
#pragma unroll
  for (int j = 0; j < 4; ++j) {
    int g = base + j;
    v[j] = (g < N_NODES) ? deg[g] : 0;
  }
  int s = v[0] + v[1] + v[2] + v[3];
  tmp[t] = s;
  __syncthreads();
  for (int d = 1; d < 256; d <<= 1) {
    int add = (t >= d) ? tmp[t - d] : 0;
    __syncthreads();
    tmp[t] += add;
    __syncthreads();
  }
  int off = tmp[t] - s;  // exclusive within block
#pragma unroll
  for (int j = 0; j < 4; ++j) {
    int g = base + j;
    if (g < N_NODES) excl[g] = off;
    off += v[j];
  }
  if (t == 255) bsum[blockIdx.x] = tmp[255];
}

__global__ void k_scan2(int* __restrict__ bsum) {
  int run = 0;
  for (int i = 0; i < NSCANB; ++i) {
    int t = bsum[i];
    bsum[i] = run;
    run += t;
  }
}

// cursor = global exclusive scan; also dinv = rsqrt(deg+1)  (self-loop)
__global__ void k_scan3(const int* __restrict__ excl, const int* __restrict__ bsum,
                        const int* __restrict__ deg, int* __restrict__ cursor,
                        float* __restrict__ dinv) {
  int i = blockIdx.x * 256 + threadIdx.x;
  if (i < N_NODES) {
    cursor[i] = excl[i] + bsum[i / SCAN_B];
    dinv[i] = rsqrtf((float)deg[i] + 1.0f);
  }
}

__global__ void k_fill(const int* __restrict__ row, const int* __restrict__ col,
                       int* __restrict__ cursor, int* __restrict__ csr_src) {
  int e = blockIdx.x * 256 + threadIdx.x;
  if (e < N_EDGES) {
    int pos = atomicAdd(&cursor[col[e]], 1);
    csr_src[pos] = row[e];
  }
}
// after k_fill: cursor[n] = end of n's slot range; start = cursor[n] - deg[n]

// ---------------- GEMM: hs[n, kout] = dinv[n] * (relu?(X[n,:]) @ W) ----------------

template <bool RELU_IN>
__global__ __launch_bounds__(256) void k_gemm(const float* __restrict__ X,
                                              const float* __restrict__ W,
                                              const float* __restrict__ dinv,
                                              float* __restrict__ Y,
                                              int n_rows, int kout) {
  constexpr int K = 128;
  constexpr int CT = 64;
  constexpr int ROWS = 32;
  constexpr int XS = K + 4;
  __shared__ float Wl[K][CT];
  __shared__ float Xl[ROWS][XS];

  const int tid = threadIdx.x;
  const int col0 = blockIdx.y * CT;

  for (int i = tid; i < K * CT / 4; i += 256) {
    int k = i >> 4, q = i & 15;
    *(float4*)&Wl[k][q * 4] = *(const float4*)&W[k * kout + col0 + q * 4];
  }

  const int colq = tid & 15;
  const int rs = tid >> 4;
  const int r0 = rs * 2, r1 = rs * 2 + 1;
  const int nchunks = (n_rows + ROWS - 1) / ROWS;

  for (int chunk = blockIdx.x; chunk < nchunks; chunk += gridDim.x) {
    const int base = chunk * ROWS;
    const int nr = min(ROWS, n_rows - base);
    __syncthreads();
    for (int i = tid; i < ROWS * K / 4; i += 256) {
      int r = i >> 5, q = i & 31;
      if (r < nr) {
        float4 v = *(const float4*)&X[(long long)(base + r) * K + q * 4];
        if (RELU_IN) {
          v.x = fmaxf(v.x, 0.f); v.y = fmaxf(v.y, 0.f);
          v.z = fmaxf(v.z, 0.f); v.w = fmaxf(v.w, 0.f);
        }
        *(float4*)&Xl[r][q * 4] = v;
      }
    }
    __syncthreads();

    float4 a0 = {0, 0, 0, 0}, a1 = {0, 0, 0, 0};
#pragma unroll 8
    for (int k = 0; k < K; ++k) {
      float4 w = *(float4*)&Wl[k][colq * 4];
      float x0 = Xl[r0][k], x1 = Xl[r1][k];
      a0.x += x0 * w.x; a0.y += x0 * w.y; a0.z += x0 * w.z; a0.w += x0 * w.w;
      a1.x += x1 * w.x; a1.y += x1 * w.y; a1.z += x1 * w.z; a1.w += x1 * w.w;
    }
    if (r0 < nr) {
      float s0 = dinv[base + r0];
      a0.x *= s0; a0.y *= s0; a0.z *= s0; a0.w *= s0;
      *(float4*)&Y[(long long)(base + r0) * kout + col0 + colq * 4] = a0;
    }
    if (r1 < nr) {
      float s1 = dinv[base + r1];
      a1.x *= s1; a1.y *= s1; a1.z *= s1; a1.w *= s1;
      *(float4*)&Y[(long long)(base + r1) * kout + col0 + colq * 4] = a1;
    }
  }
}

// ---------- gather: out[n] = bias + dinv[n] * (hs[n] + sum_{src in CSR(n)} hs[src]) ----------

template <int C>
__global__ __launch_bounds__(256) void k_gather(const int* __restrict__ cursor,
                                                const int* __restrict__ deg,
                                                const int* __restrict__ csr_src,
                                                const float* __restrict__ dinv,
                                                const float* __restrict__ hs,
                                                const float* __restrict__ bias,
                                                float* __restrict__ out) {
  constexpr int Q = C / 4;
  int idx = blockIdx.x * 256 + threadIdx.x;
  if (idx >= N_NODES * Q) return;
  int n = idx / Q, q = idx % Q;
  float d = dinv[n];
  int end = cursor[n];
  int dg = deg[n];
  float4 bv = *(const float4*)&bias[q * 4];
  float4 acc = *(const float4*)&hs[(long long)n * C + q * 4];  // self-loop term
  for (int s = end - dg; s < end; ++s) {
    int src = csr_src[s];
    float4 v = *(const float4*)&hs[(long long)src * C + q * 4];
    acc.x += v.x; acc.y += v.y; acc.z += v.z; acc.w += v.w;
  }
  float4 o = {bv.x + d * acc.x, bv.y + d * acc.y, bv.z + d * acc.z, bv.w + d * acc.w};
  *(float4*)&out[(long long)n * C + q * 4] = o;
}

// ---------------- launch ----------------

extern "C" void kernel_launch(void* const* d_in, const int* in_sizes, int n_in,
                              void* d_out, int out_size, void* d_ws, size_t ws_size,
                              hipStream_t stream) {
  const float* x = (const float*)d_in[0];
  const int* ei = (const int*)d_in[1];
  const int* erow = ei;            // sources
  const int* ecol = ei + N_EDGES;  // targets
  const float* W1 = (const float*)d_in[2];
  const float* b1 = (const float*)d_in[3];
  const float* W2 = (const float*)d_in[4];
  const float* b2 = (const float*)d_in[5];
  float* out = (float*)d_out;

  char* ws = (char*)d_ws;
  int* deg = (int*)(ws + 0);                     // 400,000 B
  int* cursor = (int*)(ws + 400128);             // 400,000 B
  int* excl = (int*)(ws + 800256);               // 400,000 B
  int* bsum = (int*)(ws + 1200384);              // 512 B
  int* csr_src = (int*)(ws + 1200896);           // 2,560,000 B
  float* dinv = (float*)(ws + 3760896);          // 400,000 B
  float* hs1 = (float*)(ws + 4161024);           // 51,200,000 B
  float* agg1 = (float*)(ws + 55361024);         // 51,200,000 B
  float* hs2 = hs1;                              // hs1 dead after gather1; reuse

  // CSR build
  k_zero_i32<<<(N_NODES + 255) / 256, 256, 0, stream>>>(deg, N_NODES);
  k_hist<<<(N_EDGES + 255) / 256, 256, 0, stream>>>(ecol, deg);
  k_scan1<<<NSCANB, 256, 0, stream>>>(deg, excl, bsum);
  k_scan2<<<1, 1, 0, stream>>>(bsum);
  k_scan3<<<(N_NODES + 255) / 256, 256, 0, stream>>>(excl, bsum, deg, cursor, dinv);
  k_fill<<<(N_EDGES + 255) / 256, 256, 0, stream>>>(erow, ecol, cursor, csr_src);

  // layer 1: hs1 = dinv * (x @ W1); agg1 = b1 + dinv*(hs1 + gather)
  dim3 g1((N_NODES + 31) / 32, 2);
  k_gemm<false><<<g1, 256, 0, stream>>>(x, W1, dinv, hs1, N_NODES, 128);
  k_gather<128><<<(N_NODES * 32 + 255) / 256, 256, 0, stream>>>(cursor, deg, csr_src, dinv,
                                                                hs1, b1, agg1);

  // layer 2: hs2 = dinv * (relu(agg1) @ W2); out = b2 + dinv*(hs2 + gather)
  dim3 g2((N_NODES + 31) / 32, 1);
  k_gemm<true><<<g2, 256, 0, stream>>>(agg1, W2, dinv, hs2, N_NODES, 64);
  k_gather<64><<<(N_NODES * 16 + 255) / 256, 256, 0, stream>>>(cursor, deg, csr_src, dinv,
                                                               hs2, b2, out);
}

// Round 3
// 255.483 us; speedup vs baseline: 6.9388x; 1.0382x over previous
//
#include <hip/hip_runtime.h>

namespace {
constexpr int N_NODES = 100000;
constexpr int N_EDGES = 640000;
constexpr int SCAN_B = 1024;
constexpr int NSCANB = (N_NODES + SCAN_B - 1) / SCAN_B;  // 98
}

// ---------------- CSR build ----------------

__global__ void k_zero_i32(int* __restrict__ p, int n) {
  int i = blockIdx.x * 256 + threadIdx.x;
  if (i < n) p[i] = 0;
}

__global__ void k_hist(const int* __restrict__ col, int* __restrict__ deg) {
  int i = blockIdx.x * 256 + threadIdx.x;
  if (i < N_EDGES) atomicAdd(&deg[col[i]], 1);
}

__global__ __launch_bounds__(256) void k_scan1(const int* __restrict__ deg,
                                               int* __restrict__ excl,
                                               int* __restrict__ bsum) {
  __shared__ int tmp[256];
  int t = threadIdx.x;
  int base = blockIdx.x * SCAN_B + t * 4;
  int v[4];
#pragma unroll
  for (int j = 0; j < 4; ++j) {
    int g = base + j;
    v[j] = (g < N_NODES) ? deg[g] : 0;
  }
  int s = v[0] + v[1] + v[2] + v[3];
  tmp[t] = s;
  __syncthreads();
  for (int d = 1; d < 256; d <<= 1) {
    int add = (t >= d) ? tmp[t - d] : 0;
    __syncthreads();
    tmp[t] += add;
    __syncthreads();
  }
  int off = tmp[t] - s;
#pragma unroll
  for (int j = 0; j < 4; ++j) {
    int g = base + j;
    if (g < N_NODES) excl[g] = off;
    off += v[j];
  }
  if (t == 255) bsum[blockIdx.x] = tmp[255];
}

// parallel exclusive scan of the 98 block sums (was serial single-thread)
__global__ __launch_bounds__(128) void k_scan2(int* __restrict__ bsum) {
  __shared__ int tmp[128];
  int t = threadIdx.x;
  int v = (t < NSCANB) ? bsum[t] : 0;
  tmp[t] = v;
  __syncthreads();
  for (int d = 1; d < 128; d <<= 1) {
    int add = (t >= d) ? tmp[t - d] : 0;
    __syncthreads();
    tmp[t] += add;
    __syncthreads();
  }
  if (t < NSCANB) bsum[t] = tmp[t] - v;  // exclusive
}

__global__ void k_scan3(const int* __restrict__ excl, const int* __restrict__ bsum,
                        const int* __restrict__ deg, int* __restrict__ cursor,
                        float* __restrict__ dinv) {
  int i = blockIdx.x * 256 + threadIdx.x;
  if (i < N_NODES) {
    cursor[i] = excl[i] + bsum[i / SCAN_B];
    dinv[i] = rsqrtf((float)deg[i] + 1.0f);
  }
}

__global__ void k_fill(const int* __restrict__ row, const int* __restrict__ col,
                       int* __restrict__ cursor, int* __restrict__ csr_src) {
  int e = blockIdx.x * 256 + threadIdx.x;
  if (e < N_EDGES) {
    int pos = atomicAdd(&cursor[col[e]], 1);
    csr_src[pos] = row[e];
  }
}
// after k_fill: cursor[n] = end of n's range; start = cursor[n] - deg[n]

// ---------------- GEMM: hs[n,:] = dinv[n] * (relu?(X[n,:]) @ W) ----------------
// 64x64 tile, 4x4 register blocking, all-b128 LDS reads, async prefetch (T14).

template <bool RELU_IN>
__global__ __launch_bounds__(256) void k_gemm(const float* __restrict__ X,
                                              const float* __restrict__ W,
                                              const float* __restrict__ dinv,
                                              float* __restrict__ Y,
                                              int n_rows, int kout) {
  constexpr int K = 128;
  constexpr int BM = 64;
  constexpr int BN = 64;
  constexpr int XS = K + 4;  // 132: rows 16B-aligned, 2-way banks (free)
  __shared__ float Wl[K][BN];   // 32 KB
  __shared__ float Xl[BM][XS];  // 33.8 KB

  const int tid = threadIdx.x;
  const int tx = tid & 15;   // col quad
  const int ty = tid >> 4;   // row quad
  const int col0 = blockIdx.y * BN;

  // W tile: once per block (grid-strided chunks amortize it)
  for (int i = tid; i < K * BN / 4; i += 256) {
    int k = i >> 4, q = i & 15;
    *(float4*)&Wl[k][q * 4] = *(const float4*)&W[k * kout + col0 + q * 4];
  }

  const int nchunks = (n_rows + BM - 1) / BM;
  const int r_base = tid >> 5;  // 0..7
  const int qq = tid & 31;      // k-quad 0..31

  float4 pf[8];
  int chunk = blockIdx.x;
  {
    const int base = chunk * BM;
#pragma unroll
    for (int p = 0; p < 8; ++p) {
      int r = min(base + r_base + p * 8, n_rows - 1);
      pf[p] = *(const float4*)&X[(long long)r * K + qq * 4];
    }
  }

  for (; chunk < nchunks; chunk += gridDim.x) {
    __syncthreads();  // prior readers of Xl done (also orders after W-load issue)
#pragma unroll
    for (int p = 0; p < 8; ++p) {
      float4 v = pf[p];
      if (RELU_IN) {
        v.x = fmaxf(v.x, 0.f); v.y = fmaxf(v.y, 0.f);
        v.z = fmaxf(v.z, 0.f); v.w = fmaxf(v.w, 0.f);
      }
      *(float4*)&Xl[r_base + p * 8][qq * 4] = v;
    }
    __syncthreads();

    // issue next chunk's loads now; they complete under the k-loop
    int nchunk = chunk + gridDim.x;
    if (nchunk < nchunks) {
      const int nbase = nchunk * BM;
#pragma unroll
      for (int p = 0; p < 8; ++p) {
        int r = min(nbase + r_base + p * 8, n_rows - 1);
        pf[p] = *(const float4*)&X[(long long)r * K + qq * 4];
      }
    }

    float4 acc[4] = {{0, 0, 0, 0}, {0, 0, 0, 0}, {0, 0, 0, 0}, {0, 0, 0, 0}};
#pragma unroll 8
    for (int k0 = 0; k0 < K; k0 += 4) {
      float4 wq[4], xr[4];
#pragma unroll
      for (int j = 0; j < 4; ++j) wq[j] = *(float4*)&Wl[k0 + j][tx * 4];
#pragma unroll
      for (int r = 0; r < 4; ++r) xr[r] = *(float4*)&Xl[ty * 4 + r][k0];
#pragma unroll
      for (int r = 0; r < 4; ++r) {
        acc[r].x += xr[r].x * wq[0].x; acc[r].y += xr[r].x * wq[0].y;
        acc[r].z += xr[r].x * wq[0].z; acc[r].w += xr[r].x * wq[0].w;
        acc[r].x += xr[r].y * wq[1].x; acc[r].y += xr[r].y * wq[1].y;
        acc[r].z += xr[r].y * wq[1].z; acc[r].w += xr[r].y * wq[1].w;
        acc[r].x += xr[r].z * wq[2].x; acc[r].y += xr[r].z * wq[2].y;
        acc[r].z += xr[r].z * wq[2].z; acc[r].w += xr[r].z * wq[2].w;
        acc[r].x += xr[r].w * wq[3].x; acc[r].y += xr[r].w * wq[3].y;
        acc[r].z += xr[r].w * wq[3].z; acc[r].w += xr[r].w * wq[3].w;
      }
    }

    const int base = chunk * BM;
#pragma unroll
    for (int r = 0; r < 4; ++r) {
      int row = base + ty * 4 + r;
      if (row < n_rows) {
        float s = dinv[row];
        float4 o = {acc[r].x * s, acc[r].y * s, acc[r].z * s, acc[r].w * s};
        *(float4*)&Y[(long long)row * kout + col0 + tx * 4] = o;
      }
    }
  }
}

// ---------- gather: out[n] = bias + dinv[n] * (hs[n] + sum_{src in CSR(n)} hs[src]) ----------

template <int C>
__global__ __launch_bounds__(256) void k_gather(const int* __restrict__ cursor,
                                                const int* __restrict__ deg,
                                                const int* __restrict__ csr_src,
                                                const float* __restrict__ dinv,
                                                const float* __restrict__ hs,
                                                const float* __restrict__ bias,
                                                float* __restrict__ out) {
  constexpr int Q = C / 4;
  int idx = blockIdx.x * 256 + threadIdx.x;
  if (idx >= N_NODES * Q) return;
  int n = idx / Q, q = idx % Q;
  float d = dinv[n];
  int end = cursor[n];
  int dg = deg[n];
  float4 bv = *(const float4*)&bias[q * 4];
  float4 acc = *(const float4*)&hs[(long long)n * C + q * 4];  // self-loop
  for (int s = end - dg; s < end; ++s) {
    int src = csr_src[s];
    float4 v = *(const float4*)&hs[(long long)src * C + q * 4];
    acc.x += v.x; acc.y += v.y; acc.z += v.z; acc.w += v.w;
  }
  float4 o = {bv.x + d * acc.x, bv.y + d * acc.y, bv.z + d * acc.z, bv.w + d * acc.w};
  *(float4*)&out[(long long)n * C + q * 4] = o;
}

// ---------------- launch ----------------

extern "C" void kernel_launch(void* const* d_in, const int* in_sizes, int n_in,
                              void* d_out, int out_size, void* d_ws, size_t ws_size,
                              hipStream_t stream) {
  const float* x = (const float*)d_in[0];
  const int* ei = (const int*)d_in[1];
  const int* erow = ei;            // sources
  const int* ecol = ei + N_EDGES;  // targets
  const float* W1 = (const float*)d_in[2];
  const float* b1 = (const float*)d_in[3];
  const float* W2 = (const float*)d_in[4];
  const float* b2 = (const float*)d_in[5];
  float* out = (float*)d_out;

  char* ws = (char*)d_ws;
  int* deg = (int*)(ws + 0);
  int* cursor = (int*)(ws + 400128);
  int* excl = (int*)(ws + 800256);
  int* bsum = (int*)(ws + 1200384);
  int* csr_src = (int*)(ws + 1200896);
  float* dinv = (float*)(ws + 3760896);
  float* hs1 = (float*)(ws + 4161024);
  float* agg1 = (float*)(ws + 55361024);
  float* hs2 = hs1;  // hs1 dead after gather1

  // CSR build
  k_zero_i32<<<(N_NODES + 255) / 256, 256, 0, stream>>>(deg, N_NODES);
  k_hist<<<(N_EDGES + 255) / 256, 256, 0, stream>>>(ecol, deg);
  k_scan1<<<NSCANB, 256, 0, stream>>>(deg, excl, bsum);
  k_scan2<<<1, 128, 0, stream>>>(bsum);
  k_scan3<<<(N_NODES + 255) / 256, 256, 0, stream>>>(excl, bsum, deg, cursor, dinv);
  k_fill<<<(N_EDGES + 255) / 256, 256, 0, stream>>>(erow, ecol, cursor, csr_src);

  // layer 1
  dim3 g1(512, 2);
  k_gemm<false><<<g1, 256, 0, stream>>>(x, W1, dinv, hs1, N_NODES, 128);
  k_gather<128><<<(N_NODES * 32 + 255) / 256, 256, 0, stream>>>(cursor, deg, csr_src, dinv,
                                                                hs1, b1, agg1);

  // layer 2
  dim3 g2(512, 1);
  k_gemm<true><<<g2, 256, 0, stream>>>(agg1, W2, dinv, hs2, N_NODES, 64);
  k_gather<64><<<(N_NODES * 16 + 255) / 256, 256, 0, stream>>>(cursor, deg, csr_src, dinv,
                                                               hs2, b2, out);
}